// Round 19
// baseline (746.092 us; speedup 1.0000x reference)
//
#include <hip/hip_runtime.h>

#define N_NODES    100000
#define N_FEATURES 2000
#define HIDDEN     64
#define N_LABELS   16
#define NNZ_FEAT   5000000
#define N_EDGES    3200000
#define ITERS      10
#define ALPHA      0.1f

// coarse binning: 512 rows per bucket
#define CBSH       9
#define CROWS      (1 << CBSH)
#define NBC        ((N_NODES + CROWS - 1) >> CBSH)  // 196
#define TILE       8192                              // entries per binA block
#define NFB        ((NNZ_FEAT + TILE - 1) / TILE)    // 611
#define NEB        ((N_EDGES + TILE - 1) / TILE)     // 391
#define BCAP       28672                             // binB LDS staging capacity (112 KB)

// edge packed-entry decode constants (col 17b | w 15b fixed point)
#define EQMUL  1048544.0f            // edge w * 0.9 * 32767/0.028125 = w * 32*32767
#define EWDEC  (0.028125f / 32767.0f)

__device__ __forceinline__ unsigned short f2bf(float x) {
    unsigned u = __float_as_uint(x);
    u += 0x7FFF + ((u >> 16) & 1);          // round-to-nearest-even
    return (unsigned short)(u >> 16);
}
__device__ __forceinline__ float bf_lo(unsigned u) { return __uint_as_float(u << 16); }
__device__ __forceinline__ float bf_hi(unsigned u) { return __uint_as_float(u & 0xFFFF0000u); }

// ---- fp8 e4m3 (OCP), W1 prescaled by 16, clamped to normal range ----
__device__ __forceinline__ unsigned char f2fp8(float x) {
    float a = fabsf(x) * 16.0f;
    a = fminf(fmaxf(a, 0.015625f), 448.0f);     // [2^-6, 448]: always normal
    unsigned u = __float_as_uint(a) + 0x80000;  // round on mantissa bit 19
    int v11 = (int)((u >> 20) & 0x7FF) - 960;   // (exp-120)<<3 | mant3
    v11 = v11 < 8 ? 8 : (v11 > 126 ? 126 : v11);
    return (unsigned char)(v11 | ((__float_as_uint(x) >> 24) & 0x80));
}
#if __has_builtin(__builtin_amdgcn_cvt_f32_fp8)
#define FP8DEC(w, s) __builtin_amdgcn_cvt_f32_fp8((w), (s))
#else
__device__ __forceinline__ float fp8dec_sw(unsigned w, int s) {
    unsigned u = (w >> (8 * s)) & 0xFF;
    return __uint_as_float((((u & 0x7F) + 960) << 20) | ((u & 0x80) << 24));
}
#define FP8DEC(w, s) fp8dec_sw((w), (s))
#endif

// ======================= CSR-build kernels =======================

__global__ __launch_bounds__(256) void zero_int(int* __restrict__ p, int n) {
    int t = blockIdx.x * 256 + threadIdx.x;
    if (t < n) p[t] = 0;
}

// merged coarse hist, 4-way shadow copies, int4 loads (n % 4 == 0 for both inputs)
__global__ __launch_bounds__(256) void hist2_k(const int* __restrict__ frows, int nf,
                                               int* __restrict__ cbf,
                                               const int* __restrict__ erows, int ne,
                                               int* __restrict__ cbe) {
    __shared__ int h[4 * NBC];
    for (int i = threadIdx.x; i < 4 * NBC; i += 256) h[i] = 0;
    __syncthreads();
    const int* rows; int n; int* dst; int b0, nb;
    if (blockIdx.x < 1280) { rows = frows; n = nf; dst = cbf; b0 = blockIdx.x; nb = 1280; }
    else                   { rows = erows; n = ne; dst = cbe; b0 = blockIdx.x - 1280; nb = 768; }
    int off = (threadIdx.x & 3) * NBC;
    int stride = nb * 256;
    int n4 = n >> 2;
    const int4* rows4 = reinterpret_cast<const int4*>(rows);
    for (int i = b0 * 256 + threadIdx.x; i < n4; i += stride) {
        int4 r = rows4[i];
        atomicAdd(&h[off + (r.x >> CBSH)], 1);
        atomicAdd(&h[off + (r.y >> CBSH)], 1);
        atomicAdd(&h[off + (r.z >> CBSH)], 1);
        atomicAdd(&h[off + (r.w >> CBSH)], 1);
    }
    __syncthreads();
    for (int i = threadIdx.x; i < NBC; i += 256) {
        int v = h[i] + h[NBC + i] + h[2 * NBC + i] + h[3 * NBC + i];
        if (v) atomicAdd(&dst[i], v);
    }
}

// merged scan: block 0 -> feat, block 1 -> edge
__global__ __launch_bounds__(256) void scan2_k(const int* __restrict__ cbf,
                                               int* __restrict__ cbasef, int* __restrict__ gbf,
                                               int* __restrict__ frp,
                                               const int* __restrict__ cbe,
                                               int* __restrict__ cbasee, int* __restrict__ gbe,
                                               int* __restrict__ erp) {
    const int* cnt; int* cbase; int* gbcur; int* rp;
    if (blockIdx.x == 0) { cnt = cbf; cbase = cbasef; gbcur = gbf; rp = frp; }
    else                 { cnt = cbe; cbase = cbasee; gbcur = gbe; rp = erp; }
    __shared__ int s[256];
    int t = threadIdx.x;
    int v = (t < NBC) ? cnt[t] : 0;
    s[t] = v;
    __syncthreads();
    for (int off = 1; off < 256; off <<= 1) {
        int a = (t >= off) ? s[t - off] : 0;
        __syncthreads();
        s[t] += a;
        __syncthreads();
    }
    if (t < NBC) { cbase[t] = s[t] - v; gbcur[t] = s[t] - v; }
    if (t == NBC - 1) { cbase[NBC] = s[t]; rp[N_NODES] = s[t]; }
}

// merged binA: 1024 threads, TILE 8192, vectorized input streams.
__global__ __launch_bounds__(1024) void binA2_k(
    const int* __restrict__ frows, const int* __restrict__ fcols, const float* __restrict__ fvals,
    int* __restrict__ gbf, int* __restrict__ fpk, unsigned short* __restrict__ frl,
    const int* __restrict__ erows, const int* __restrict__ ecols, const float* __restrict__ evals,
    int* __restrict__ gbe, int* __restrict__ epk, unsigned short* __restrict__ erl)
{
    __shared__ int            staged_pk[TILE];   // 32 KB
    __shared__ unsigned short staged_rl[TILE];   // 16 KB
    __shared__ unsigned char  sbkt[TILE];        //  8 KB
    __shared__ int cnt[NBC];
    __shared__ int rstart[NBC];
    __shared__ int gbase[NBC];
    __shared__ int sc[256];

    const int* rows; const int* cols; const float* vals;
    int* gbcur; int* bpk; unsigned short* brl;
    int n, qshift, bfval; float qmul;
    int bid = blockIdx.x;
    if (bid < NFB) {
        rows = frows; cols = fcols; vals = fvals; gbcur = gbf; bpk = fpk; brl = frl;
        n = NNZ_FEAT; qshift = 16; qmul = 0.f; bfval = 1;
    } else {
        bid -= NFB;
        rows = erows; cols = ecols; vals = evals; gbcur = gbe; bpk = epk; brl = erl;
        n = N_EDGES; qshift = 17; qmul = EQMUL; bfval = 0;
    }

    int tid = threadIdx.x;
    int base = bid * TILE;
    int m = n - base; if (m > TILE) m = TILE;

    for (int i = tid; i < NBC; i += 1024) cnt[i] = 0;
    __syncthreads();

    int rbuf[8]; int cbuf[8]; float vbuf[8]; int seq[8];
    int j0 = tid * 8;
    if (m == TILE) {
        const int4* r4 = reinterpret_cast<const int4*>(rows + base) + tid * 2;
        const int4* c4 = reinterpret_cast<const int4*>(cols + base) + tid * 2;
        const float4* v4 = reinterpret_cast<const float4*>(vals + base) + tid * 2;
        int4 ra = r4[0], rb = r4[1];
        int4 ca = c4[0], cb = c4[1];
        float4 va = v4[0], vb = v4[1];
        rbuf[0]=ra.x; rbuf[1]=ra.y; rbuf[2]=ra.z; rbuf[3]=ra.w;
        rbuf[4]=rb.x; rbuf[5]=rb.y; rbuf[6]=rb.z; rbuf[7]=rb.w;
        cbuf[0]=ca.x; cbuf[1]=ca.y; cbuf[2]=ca.z; cbuf[3]=ca.w;
        cbuf[4]=cb.x; cbuf[5]=cb.y; cbuf[6]=cb.z; cbuf[7]=cb.w;
        vbuf[0]=va.x; vbuf[1]=va.y; vbuf[2]=va.z; vbuf[3]=va.w;
        vbuf[4]=vb.x; vbuf[5]=vb.y; vbuf[6]=vb.z; vbuf[7]=vb.w;
    } else {
        #pragma unroll
        for (int k = 0; k < 8; ++k) {
            int j = j0 + k;
            if (j < m) { rbuf[k] = rows[base + j]; cbuf[k] = cols[base + j]; vbuf[k] = vals[base + j]; }
        }
    }
    #pragma unroll
    for (int k = 0; k < 8; ++k) {
        int j = j0 + k;
        if (j < m) seq[k] = atomicAdd(&cnt[rbuf[k] >> CBSH], 1);
    }
    __syncthreads();

    if (tid < 256) sc[tid] = (tid < NBC) ? cnt[tid] : 0;
    __syncthreads();
    for (int off = 1; off < 256; off <<= 1) {
        int a = 0;
        if (tid < 256 && tid >= off) a = sc[tid - off];
        __syncthreads();
        if (tid < 256) sc[tid] += a;
        __syncthreads();
    }
    if (tid < NBC) rstart[tid] = sc[tid] - cnt[tid];
    __syncthreads();

    #pragma unroll
    for (int k = 0; k < 8; ++k) {
        int j = j0 + k;
        if (j < m) {
            int r = rbuf[k];
            int b = r >> CBSH;
            int q = bfval ? (int)f2bf(vbuf[k]) : __float2int_rn(vbuf[k] * qmul);
            int slot = rstart[b] + seq[k];
            staged_pk[slot] = (q << qshift) | cbuf[k];
            staged_rl[slot] = (unsigned short)(r & (CROWS - 1));
            sbkt[slot] = (unsigned char)b;
        }
    }
    __syncthreads();

    if (tid < NBC && cnt[tid] > 0) gbase[tid] = atomicAdd(&gbcur[tid], cnt[tid]);
    __syncthreads();

    #pragma unroll
    for (int k = 0; k < 8; ++k) {
        int slot = k * 1024 + tid;
        if (slot < m) {
            int b = sbkt[slot];
            int dst = gbase[b] + (slot - rstart[b]);
            bpk[dst] = staged_pk[slot];
            brl[dst] = staged_rl[slot];
        }
    }
}

// merged binB: LDS-staged within-bucket permutation -> contiguous global writes.
__global__ __launch_bounds__(1024) void binB3_k(
    const int* __restrict__ fpk, const unsigned short* __restrict__ frl,
    const int* __restrict__ cbasef, int* __restrict__ frp, int* __restrict__ fcw,
    const int* __restrict__ epk, const unsigned short* __restrict__ erl,
    const int* __restrict__ cbasee, int* __restrict__ erp, int* __restrict__ ecw)
{
    const int* bin_pk; const unsigned short* bin_rl; const int* cbase; int* rp; int* cw;
    int b = blockIdx.x;
    if (b < NBC) { bin_pk = fpk; bin_rl = frl; cbase = cbasef; rp = frp; cw = fcw; }
    else { b -= NBC; bin_pk = epk; bin_rl = erl; cbase = cbasee; rp = erp; cw = ecw; }

    int r0 = b << CBSH;
    int nrows = N_NODES - r0; if (nrows > CROWS) nrows = CROWS;
    __shared__ int staged[BCAP];          // 112 KB
    __shared__ int hist[CROWS];
    __shared__ int sc[CROWS];
    int t = threadIdx.x;
    if (t < CROWS) hist[t] = 0;
    __syncthreads();
    int s = cbase[b], e = cbase[b + 1];
    int cnt = e - s;
    for (int i = s + t; i < e; i += 1024)
        atomicAdd(&hist[bin_rl[i]], 1);
    __syncthreads();
    if (t < CROWS) sc[t] = hist[t];
    __syncthreads();
    for (int off = 1; off < CROWS; off <<= 1) {
        int a = (t >= off && t < CROWS) ? sc[t - off] : 0;
        __syncthreads();
        if (t < CROWS) sc[t] += a;
        __syncthreads();
    }
    if (t < CROWS) {
        int excl = sc[t] - hist[t];
        if (t < nrows) rp[r0 + t] = excl + s;
        hist[t] = excl;
    }
    __syncthreads();

    if (cnt <= BCAP) {
        for (int i = s + t; i < e; i += 1024) {
            int pos = atomicAdd(&hist[bin_rl[i]], 1);
            staged[pos] = bin_pk[i];
        }
        __syncthreads();
        for (int j = t; j < cnt; j += 1024)
            cw[s + j] = staged[j];
    } else {
        for (int i = s + t; i < e; i += 1024) {
            int pos = atomicAdd(&hist[bin_rl[i]], 1);
            cw[s + pos] = bin_pk[i];
        }
    }
}

// ======================= compute kernels =======================

__global__ __launch_bounds__(256) void w1_to_fp8(const float* __restrict__ W1,
                                                 unsigned char* __restrict__ W1q) {
    int t = blockIdx.x * 256 + threadIdx.x;
    if (t < N_FEATURES * HIDDEN / 4) {
        float4 v = reinterpret_cast<const float4*>(W1)[t];
        uchar4 o;
        o.x = f2fp8(v.x); o.y = f2fp8(v.y); o.z = f2fp8(v.z); o.w = f2fp8(v.w);
        reinterpret_cast<uchar4*>(W1q)[t] = o;
    }
}

// Fused SpMM+MLP: 8 lanes/row, 8 hidden dims/lane, W1 fp8 L2-gather (64B row = 1 txn).
__global__ __launch_bounds__(256) void spmm_fused(const int* __restrict__ rp,
                                                  const int* __restrict__ cwp,
                                                  const unsigned char* __restrict__ W1q,
                                                  const float* __restrict__ b1,
                                                  const float* __restrict__ W2,
                                                  const float* __restrict__ b2,
                                                  unsigned short* __restrict__ az,
                                                  unsigned short* __restrict__ pb0) {
    __shared__ float sW2T[N_LABELS * (HIDDEN + 1)];   // [l][h], stride 65
    __shared__ float sb1[HIDDEN];
    __shared__ float sb2[N_LABELS];
    for (int i = threadIdx.x; i < HIDDEN * N_LABELS; i += 256) {
        int h = i >> 4, l = i & 15;
        sW2T[l * (HIDDEN + 1) + h] = W2[i];
    }
    if (threadIdx.x < HIDDEN) sb1[threadIdx.x] = b1[threadIdx.x];
    if (threadIdx.x < N_LABELS) sb2[threadIdx.x] = b2[threadIdx.x];
    __syncthreads();

    int t = blockIdx.x * 256 + threadIdx.x;
    int row = t >> 3, sl = t & 7;
    if (row >= N_NODES) return;
    int s = rp[row], e = rp[row + 1];
    int hbase = sl * 8;

    float acc[8];
    #pragma unroll
    for (int j = 0; j < 8; ++j) acc[j] = 0.f;

    int i = s;
    for (; i + 3 < e; i += 4) {
        uint2 wv[4]; float vv[4];
        #pragma unroll
        for (int k = 0; k < 4; ++k) {
            int pk = cwp[i + k];
            vv[k] = bf_hi((unsigned)pk);
            wv[k] = *reinterpret_cast<const uint2*>(W1q + (size_t)(pk & 0x7FF) * HIDDEN + hbase);
        }
        #pragma unroll
        for (int k = 0; k < 4; ++k) {
            acc[0] = fmaf(vv[k], FP8DEC(wv[k].x, 0), acc[0]);
            acc[1] = fmaf(vv[k], FP8DEC(wv[k].x, 1), acc[1]);
            acc[2] = fmaf(vv[k], FP8DEC(wv[k].x, 2), acc[2]);
            acc[3] = fmaf(vv[k], FP8DEC(wv[k].x, 3), acc[3]);
            acc[4] = fmaf(vv[k], FP8DEC(wv[k].y, 0), acc[4]);
            acc[5] = fmaf(vv[k], FP8DEC(wv[k].y, 1), acc[5]);
            acc[6] = fmaf(vv[k], FP8DEC(wv[k].y, 2), acc[6]);
            acc[7] = fmaf(vv[k], FP8DEC(wv[k].y, 3), acc[7]);
        }
    }
    for (; i < e; ++i) {
        int pk = cwp[i];
        float v = bf_hi((unsigned)pk);
        uint2 w = *reinterpret_cast<const uint2*>(W1q + (size_t)(pk & 0x7FF) * HIDDEN + hbase);
        acc[0] = fmaf(v, FP8DEC(w.x, 0), acc[0]);
        acc[1] = fmaf(v, FP8DEC(w.x, 1), acc[1]);
        acc[2] = fmaf(v, FP8DEC(w.x, 2), acc[2]);
        acc[3] = fmaf(v, FP8DEC(w.x, 3), acc[3]);
        acc[4] = fmaf(v, FP8DEC(w.y, 0), acc[4]);
        acc[5] = fmaf(v, FP8DEC(w.y, 1), acc[5]);
        acc[6] = fmaf(v, FP8DEC(w.y, 2), acc[6]);
        acc[7] = fmaf(v, FP8DEC(w.y, 3), acc[7]);
    }

    float part[16];
    #pragma unroll
    for (int l = 0; l < 16; ++l) part[l] = 0.f;
    #pragma unroll
    for (int j = 0; j < 8; ++j) {
        float a = fmaf(acc[j], 0.0625f, sb1[hbase + j]);   // un-scale fp8 x16
        a = a > 0.f ? a : 0.f;
        #pragma unroll
        for (int l = 0; l < 16; ++l)
            part[l] = fmaf(a, sW2T[l * (HIDDEN + 1) + hbase + j], part[l]);
    }
    #pragma unroll
    for (int l = 0; l < 8; ++l) {
        float lo = __shfl_xor(part[l], 1);
        float hi = __shfl_xor(part[l + 8], 1);
        part[l] = (sl & 1) ? (part[l + 8] + hi) : (part[l] + lo);
    }
    #pragma unroll
    for (int l = 0; l < 4; ++l) {
        float lo = __shfl_xor(part[l], 2);
        float hi = __shfl_xor(part[l + 4], 2);
        part[l] = (sl & 2) ? (part[l + 4] + hi) : (part[l] + lo);
    }
    #pragma unroll
    for (int l = 0; l < 2; ++l) {
        float lo = __shfl_xor(part[l], 4);
        float hi = __shfl_xor(part[l + 2], 4);
        part[l] = (sl & 4) ? (part[l + 2] + hi) : (part[l] + lo);
    }
    int lbase = 8 * (sl & 1) + 4 * ((sl >> 1) & 1) + 2 * ((sl >> 2) & 1);
    float z0 = part[0] + sb2[lbase];
    float z1 = part[1] + sb2[lbase + 1];
    unsigned oz = (unsigned)f2bf(z0) | ((unsigned)f2bf(z1) << 16);
    unsigned oa = (unsigned)f2bf(ALPHA * z0) | ((unsigned)f2bf(ALPHA * z1) << 16);
    *reinterpret_cast<unsigned*>(pb0 + (size_t)row * N_LABELS + lbase) = oz;
    *reinterpret_cast<unsigned*>(az  + (size_t)row * N_LABELS + lbase) = oa;
}

// 8 lanes/row, 4B gathers via NONTEMPORAL loads (L1 bypass -> deeper miss queue).
__global__ __launch_bounds__(256) void prop_bf16(const int* __restrict__ rp,
                                                 const int* __restrict__ cwp,
                                                 const unsigned short* __restrict__ az,
                                                 const unsigned short* __restrict__ pin,
                                                 unsigned short* __restrict__ pout) {
    int t = blockIdx.x * 256 + threadIdx.x;
    int row = t >> 3, sub = t & 7;
    if (row >= N_NODES) return;
    int s = rp[row], e = rp[row + 1];
    unsigned azw = *reinterpret_cast<const unsigned*>(az + (size_t)row * N_LABELS + sub * 2);
    float a0 = bf_lo(azw), a1 = bf_hi(azw);
    int i = s;
    for (; i + 7 < e; i += 8) {
        int cwv = cwp[i + sub];             // lane-parallel, 32B coalesced per group
        unsigned q[8]; float w[8];
        #pragma unroll
        for (int k = 0; k < 8; ++k) {
            int pk = __shfl(cwv, k, 8);
            w[k] = (float)((unsigned)pk >> 17) * EWDEC;
            q[k] = __builtin_nontemporal_load(
                reinterpret_cast<const unsigned*>(pin + (size_t)(pk & 0x1FFFF) * N_LABELS + sub * 2));
        }
        #pragma unroll
        for (int k = 0; k < 8; ++k) {
            a0 = fmaf(w[k], bf_lo(q[k]), a0);
            a1 = fmaf(w[k], bf_hi(q[k]), a1);
        }
    }
    for (; i < e; ++i) {
        int pk = cwp[i];
        float w = (float)((unsigned)pk >> 17) * EWDEC;
        unsigned q = __builtin_nontemporal_load(
            reinterpret_cast<const unsigned*>(pin + (size_t)(pk & 0x1FFFF) * N_LABELS + sub * 2));
        a0 = fmaf(w, bf_lo(q), a0);
        a1 = fmaf(w, bf_hi(q), a1);
    }
    *reinterpret_cast<unsigned*>(pout + (size_t)row * N_LABELS + sub * 2) =
        (unsigned)f2bf(a0) | ((unsigned)f2bf(a1) << 16);
}

// last iteration fused with log_softmax (8-lane shuffle reduce); writes f32 out
__global__ __launch_bounds__(256) void prop_final(const int* __restrict__ rp,
                                                  const int* __restrict__ cwp,
                                                  const unsigned short* __restrict__ az,
                                                  const unsigned short* __restrict__ pin,
                                                  float* __restrict__ out) {
    int t = blockIdx.x * 256 + threadIdx.x;
    int row = t >> 3, sub = t & 7;
    if (row >= N_NODES) return;
    int s = rp[row], e = rp[row + 1];
    unsigned azw = *reinterpret_cast<const unsigned*>(az + (size_t)row * N_LABELS + sub * 2);
    float a0 = bf_lo(azw), a1 = bf_hi(azw);
    int i = s;
    for (; i + 7 < e; i += 8) {
        int cwv = cwp[i + sub];
        unsigned q[8]; float w[8];
        #pragma unroll
        for (int k = 0; k < 8; ++k) {
            int pk = __shfl(cwv, k, 8);
            w[k] = (float)((unsigned)pk >> 17) * EWDEC;
            q[k] = __builtin_nontemporal_load(
                reinterpret_cast<const unsigned*>(pin + (size_t)(pk & 0x1FFFF) * N_LABELS + sub * 2));
        }
        #pragma unroll
        for (int k = 0; k < 8; ++k) {
            a0 = fmaf(w[k], bf_lo(q[k]), a0);
            a1 = fmaf(w[k], bf_hi(q[k]), a1);
        }
    }
    for (; i < e; ++i) {
        int pk = cwp[i];
        float w = (float)((unsigned)pk >> 17) * EWDEC;
        unsigned q = __builtin_nontemporal_load(
            reinterpret_cast<const unsigned*>(pin + (size_t)(pk & 0x1FFFF) * N_LABELS + sub * 2));
        a0 = fmaf(w, bf_lo(q), a0);
        a1 = fmaf(w, bf_hi(q), a1);
    }
    float m = fmaxf(a0, a1);
    m = fmaxf(m, __shfl_xor(m, 1));
    m = fmaxf(m, __shfl_xor(m, 2));
    m = fmaxf(m, __shfl_xor(m, 4));
    float ssum = __expf(a0 - m) + __expf(a1 - m);
    ssum += __shfl_xor(ssum, 1);
    ssum += __shfl_xor(ssum, 2);
    ssum += __shfl_xor(ssum, 4);
    float lse = m + __logf(ssum);
    *reinterpret_cast<float2*>(out + (size_t)row * N_LABELS + sub * 2) =
        make_float2(a0 - lse, a1 - lse);
}

// ======================= fallback (atomic path) =======================

__global__ __launch_bounds__(256) void zero_f4(float4* __restrict__ p, int n4) {
    int t = blockIdx.x * 256 + threadIdx.x;
    if (t < n4) p[t] = make_float4(0.f, 0.f, 0.f, 0.f);
}

__global__ __launch_bounds__(256) void spmm_feat_atomic(
    const int* __restrict__ rows, const int* __restrict__ cols,
    const float* __restrict__ vals, const float* __restrict__ W1,
    float* __restrict__ latent)
{
    long long t = (long long)blockIdx.x * 256 + threadIdx.x;
    if (t >= (long long)NNZ_FEAT * 16) return;
    int e  = (int)(t >> 4);
    int dg = (int)(t & 15);
    int r = rows[e]; int c = cols[e]; float v = vals[e];
    float4 w = *reinterpret_cast<const float4*>(W1 + (size_t)c * HIDDEN + dg * 4);
    float* dst = latent + (size_t)r * HIDDEN + dg * 4;
    atomicAdd(dst + 0, v * w.x); atomicAdd(dst + 1, v * w.y);
    atomicAdd(dst + 2, v * w.z); atomicAdd(dst + 3, v * w.w);
}

__global__ __launch_bounds__(256) void compute_z(const float* __restrict__ latent,
                                                 const float* __restrict__ b1,
                                                 const float* __restrict__ W2,
                                                 const float* __restrict__ b2,
                                                 float* __restrict__ z) {
    __shared__ float sW2[HIDDEN * N_LABELS];
    __shared__ float sb1[HIDDEN];
    for (int i = threadIdx.x; i < HIDDEN * N_LABELS; i += 256) sW2[i] = W2[i];
    if (threadIdx.x < HIDDEN) sb1[threadIdx.x] = b1[threadIdx.x];
    __syncthreads();
    int t = blockIdx.x * 256 + threadIdx.x;
    int node = t >> 4;
    int l = t & 15;
    if (node >= N_NODES) return;
    float acc = b2[l];
    const float* lat = latent + (size_t)node * HIDDEN;
    #pragma unroll 8
    for (int h = 0; h < HIDDEN; ++h) {
        float a = lat[h] + sb1[h];
        a = a > 0.f ? a : 0.f;
        acc = fmaf(a, sW2[h * N_LABELS + l], acc);
    }
    z[(size_t)node * N_LABELS + l] = acc;
}

__global__ __launch_bounds__(256) void init_acc(const float* __restrict__ z,
                                                float* __restrict__ acc) {
    int t = blockIdx.x * 256 + threadIdx.x;
    if (t < N_NODES * N_LABELS / 4) {
        float4 zv = reinterpret_cast<const float4*>(z)[t];
        reinterpret_cast<float4*>(acc)[t] =
            make_float4(ALPHA * zv.x, ALPHA * zv.y, ALPHA * zv.z, ALPHA * zv.w);
    }
}

__global__ __launch_bounds__(256) void edge_scatter(
    const int* __restrict__ rows, const int* __restrict__ cols,
    const float* __restrict__ w, const float* __restrict__ p,
    float* __restrict__ acc)
{
    long long t = (long long)blockIdx.x * 256 + threadIdx.x;
    if (t >= (long long)N_EDGES * 4) return;
    int e = (int)(t >> 2);
    int part = (int)(t & 3);
    int r = rows[e]; int c = cols[e];
    float wt = w[e] * (1.0f - ALPHA);
    float4 pv = *reinterpret_cast<const float4*>(p + (size_t)c * N_LABELS + part * 4);
    float* dst = acc + (size_t)r * N_LABELS + part * 4;
    atomicAdd(dst + 0, wt * pv.x); atomicAdd(dst + 1, wt * pv.y);
    atomicAdd(dst + 2, wt * pv.z); atomicAdd(dst + 3, wt * pv.w);
}

__global__ __launch_bounds__(256) void logsoftmax_k(const float* __restrict__ p,
                                                    float* __restrict__ out) {
    int node = blockIdx.x * 256 + threadIdx.x;
    if (node >= N_NODES) return;
    const float4* src = reinterpret_cast<const float4*>(p + (size_t)node * N_LABELS);
    float4 a = src[0], b = src[1], c = src[2], d = src[3];
    float x[16] = {a.x,a.y,a.z,a.w, b.x,b.y,b.z,b.w, c.x,c.y,c.z,c.w, d.x,d.y,d.z,d.w};
    float m = x[0];
    #pragma unroll
    for (int i = 1; i < 16; ++i) m = fmaxf(m, x[i]);
    float s = 0.f;
    #pragma unroll
    for (int i = 0; i < 16; ++i) s += expf(x[i] - m);
    float lse = m + logf(s);
    float4* o = reinterpret_cast<float4*>(out + (size_t)node * N_LABELS);
    o[0] = make_float4(x[0]-lse,  x[1]-lse,  x[2]-lse,  x[3]-lse);
    o[1] = make_float4(x[4]-lse,  x[5]-lse,  x[6]-lse,  x[7]-lse);
    o[2] = make_float4(x[8]-lse,  x[9]-lse,  x[10]-lse, x[11]-lse);
    o[3] = make_float4(x[12]-lse, x[13]-lse, x[14]-lse, x[15]-lse);
}

// ======================= launch =======================

extern "C" void kernel_launch(void* const* d_in, const int* in_sizes, int n_in,
                              void* d_out, int out_size, void* d_ws, size_t ws_size,
                              hipStream_t stream)
{
    const int*   feat_rows = (const int*)d_in[0];
    const int*   feat_cols = (const int*)d_in[1];
    const float* feat_vals = (const float*)d_in[2];
    const int*   edge_rows = (const int*)d_in[3];
    const int*   edge_cols = (const int*)d_in[4];
    const float* edge_w    = (const float*)d_in[5];
    const float* W1 = (const float*)d_in[6];
    const float* b1 = (const float*)d_in[7];
    const float* W2 = (const float*)d_in[8];
    const float* b2 = (const float*)d_in[9];
    float* out = (float*)d_out;

    // ---- workspace layout (4-byte words) ----
    size_t need = 0;
    size_t o_feat_cw = need; need += (size_t)NNZ_FEAT;            // packed int32, 20 MB
    size_t o_edge_cw = need; need += (size_t)N_EDGES;             // packed int32, 12.8 MB
    size_t o_latent  = need; need += (size_t)N_NODES * HIDDEN;    // 25.6 MB (fallback + feat-bin alias)
    size_t o_z       = need; need += (size_t)N_NODES * N_LABELS;  // az (bf16) + feat_rl alias
    size_t o_p0      = need; need += (size_t)N_NODES * N_LABELS;
    size_t o_p1      = need; need += (size_t)N_NODES * N_LABELS;
    size_t o_frp     = need; need += N_NODES + 1;
    size_t o_erp     = need; need += N_NODES + 1;
    size_t o_w1q     = need; need += (size_t)N_FEATURES * HIDDEN / 4;  // fp8 W1, 128 KB
    size_t o_ebin_pk = need; need += (size_t)N_EDGES;             // dedicated edge bin, 12.8 MB
    size_t o_ebin_rl = need; need += (size_t)N_EDGES / 2;         // 6.4 MB
    size_t o_cbf     = need; need += NBC;
    size_t o_cbe     = need; need += NBC;
    size_t o_cbasef  = need; need += NBC + 1;
    size_t o_cbasee  = need; need += NBC + 1;
    size_t o_gbf     = need; need += NBC;
    size_t o_gbe     = need; need += NBC;
    size_t need_bytes = need * 4 + 64;

    float* base = (float*)d_ws;
    float* latent = base + o_latent;
    float* z  = base + o_z;
    float* p0 = base + o_p0;
    float* p1 = base + o_p1;

    if (ws_size >= need_bytes) {
        int* feat_cw = (int*)(base + o_feat_cw);
        int* edge_cw = (int*)(base + o_edge_cw);
        int* feat_rp = (int*)(base + o_frp);
        int* edge_rp = (int*)(base + o_erp);
        unsigned char* W1q = (unsigned char*)(base + o_w1q);
        int* cbf    = (int*)(base + o_cbf);
        int* cbe    = (int*)(base + o_cbe);
        int* cbasef = (int*)(base + o_cbasef);
        int* cbasee = (int*)(base + o_cbasee);
        int* gbf    = (int*)(base + o_gbf);
        int* gbe    = (int*)(base + o_gbe);
        int*            fbin_pk = (int*)(base + o_latent);            // 5M ints <= 6.4M
        unsigned short* fbin_rl = (unsigned short*)(base + o_z);      // 5M shorts <= 6.4M (z+p0)
        int*            ebin_pk = (int*)(base + o_ebin_pk);
        unsigned short* ebin_rl = (unsigned short*)(base + o_ebin_rl);
        unsigned short* az  = (unsigned short*)z;                     // bf16 anchor, 3.2 MB
        unsigned short* pb0 = (unsigned short*)p0;
        unsigned short* pb1 = (unsigned short*)p1;

        // ---- merged CSR builds ----
        w1_to_fp8<<<(N_FEATURES * HIDDEN / 4 + 255) / 256, 256, 0, stream>>>(W1, W1q);
        zero_int<<<2, 256, 0, stream>>>(cbf, 2 * NBC);   // cbf,cbe adjacent
        hist2_k<<<2048, 256, 0, stream>>>(feat_rows, NNZ_FEAT, cbf, edge_rows, N_EDGES, cbe);
        scan2_k<<<2, 256, 0, stream>>>(cbf, cbasef, gbf, feat_rp, cbe, cbasee, gbe, edge_rp);
        binA2_k<<<NFB + NEB, 1024, 0, stream>>>(
            feat_rows, feat_cols, feat_vals, gbf, fbin_pk, fbin_rl,
            edge_rows, edge_cols, edge_w, gbe, ebin_pk, ebin_rl);
        binB3_k<<<2 * NBC, 1024, 0, stream>>>(
            fbin_pk, fbin_rl, cbasef, feat_rp, feat_cw,
            ebin_pk, ebin_rl, cbasee, edge_rp, edge_cw);

        // ---- layer 1 + z (fused; writes az bf16 + p0 bf16) ----
        spmm_fused<<<(N_NODES * 8 + 255) / 256, 256, 0, stream>>>(
            feat_rp, feat_cw, W1q, b1, W2, b2, az, pb0);

        // ---- propagation (bf16 state, 8 lanes/row, nontemporal gathers) ----
        const unsigned short* pin = pb0;
        int pgrid = (N_NODES * 8 + 255) / 256;
        for (int it = 0; it < ITERS - 1; ++it) {
            unsigned short* pout = (it & 1) ? pb0 : pb1;
            prop_bf16<<<pgrid, 256, 0, stream>>>(edge_rp, edge_cw, az, pin, pout);
            pin = pout;
        }
        prop_final<<<pgrid, 256, 0, stream>>>(edge_rp, edge_cw, az, pin, out);
    } else {
        // ---- fallback: atomic path ----
        int n4 = N_NODES * HIDDEN / 4;
        zero_f4<<<(n4 + 255) / 256, 256, 0, stream>>>((float4*)latent, n4);
        long long total = (long long)NNZ_FEAT * 16;
        spmm_feat_atomic<<<(int)((total + 255) / 256), 256, 0, stream>>>(
            feat_rows, feat_cols, feat_vals, W1, latent);
        compute_z<<<N_NODES * 16 / 256, 256, 0, stream>>>(latent, b1, W2, b2, z);
        const float* pin = z;
        float* bufs[2] = {p0, p1};
        for (int it = 0; it < ITERS; ++it) {
            float* pout = bufs[it & 1];
            init_acc<<<(N_NODES * N_LABELS / 4 + 255) / 256, 256, 0, stream>>>(z, pout);
            long long tot = (long long)N_EDGES * 4;
            edge_scatter<<<(int)((tot + 255) / 256), 256, 0, stream>>>(
                edge_rows, edge_cols, edge_w, pin, pout);
            pin = pout;
        }
        logsoftmax_k<<<(N_NODES + 255) / 256, 256, 0, stream>>>(pin, out);
    }
}

// Round 20
// 458.806 us; speedup vs baseline: 1.6262x; 1.6262x over previous
//
#include <hip/hip_runtime.h>

#define N_NODES    100000
#define N_FEATURES 2000
#define HIDDEN     64
#define N_LABELS   16
#define NNZ_FEAT   5000000
#define N_EDGES    3200000
#define ITERS      10
#define ALPHA      0.1f

// coarse binning: 512 rows per bucket
#define CBSH       9
#define CROWS      (1 << CBSH)
#define NBC        ((N_NODES + CROWS - 1) >> CBSH)  // 196
#define TILE       8192                              // entries per binA block
#define NFB        ((NNZ_FEAT + TILE - 1) / TILE)    // 611
#define NEB        ((N_EDGES + TILE - 1) / TILE)     // 391
#define BCAP       28672                             // binB LDS staging capacity (112 KB)

// edge packed-entry decode constants (col 17b | w 15b fixed point)
#define EQMUL  1048544.0f            // edge w * 0.9 * 32767/0.028125 = w * 32*32767
#define EWDEC  (0.028125f / 32767.0f)

__device__ __forceinline__ unsigned short f2bf(float x) {
    unsigned u = __float_as_uint(x);
    u += 0x7FFF + ((u >> 16) & 1);          // round-to-nearest-even
    return (unsigned short)(u >> 16);
}
__device__ __forceinline__ float bf_lo(unsigned u) { return __uint_as_float(u << 16); }
__device__ __forceinline__ float bf_hi(unsigned u) { return __uint_as_float(u & 0xFFFF0000u); }

// ---- fp8 e4m3 (OCP), W1 prescaled by 16, clamped to normal range ----
__device__ __forceinline__ unsigned char f2fp8(float x) {
    float a = fabsf(x) * 16.0f;
    a = fminf(fmaxf(a, 0.015625f), 448.0f);     // [2^-6, 448]: always normal
    unsigned u = __float_as_uint(a) + 0x80000;  // round on mantissa bit 19
    int v11 = (int)((u >> 20) & 0x7FF) - 960;   // (exp-120)<<3 | mant3
    v11 = v11 < 8 ? 8 : (v11 > 126 ? 126 : v11);
    return (unsigned char)(v11 | ((__float_as_uint(x) >> 24) & 0x80));
}
#if __has_builtin(__builtin_amdgcn_cvt_f32_fp8)
#define FP8DEC(w, s) __builtin_amdgcn_cvt_f32_fp8((w), (s))
#else
__device__ __forceinline__ float fp8dec_sw(unsigned w, int s) {
    unsigned u = (w >> (8 * s)) & 0xFF;
    return __uint_as_float((((u & 0x7F) + 960) << 20) | ((u & 0x80) << 24));
}
#define FP8DEC(w, s) fp8dec_sw((w), (s))
#endif

// ======================= CSR-build kernels =======================

__global__ __launch_bounds__(256) void zero_int(int* __restrict__ p, int n) {
    int t = blockIdx.x * 256 + threadIdx.x;
    if (t < n) p[t] = 0;
}

// merged coarse hist, 4-way shadow copies, int4 loads (n % 4 == 0 for both inputs)
__global__ __launch_bounds__(256) void hist2_k(const int* __restrict__ frows, int nf,
                                               int* __restrict__ cbf,
                                               const int* __restrict__ erows, int ne,
                                               int* __restrict__ cbe) {
    __shared__ int h[4 * NBC];
    for (int i = threadIdx.x; i < 4 * NBC; i += 256) h[i] = 0;
    __syncthreads();
    const int* rows; int n; int* dst; int b0, nb;
    if (blockIdx.x < 1280) { rows = frows; n = nf; dst = cbf; b0 = blockIdx.x; nb = 1280; }
    else                   { rows = erows; n = ne; dst = cbe; b0 = blockIdx.x - 1280; nb = 768; }
    int off = (threadIdx.x & 3) * NBC;
    int stride = nb * 256;
    int n4 = n >> 2;
    const int4* rows4 = reinterpret_cast<const int4*>(rows);
    for (int i = b0 * 256 + threadIdx.x; i < n4; i += stride) {
        int4 r = rows4[i];
        atomicAdd(&h[off + (r.x >> CBSH)], 1);
        atomicAdd(&h[off + (r.y >> CBSH)], 1);
        atomicAdd(&h[off + (r.z >> CBSH)], 1);
        atomicAdd(&h[off + (r.w >> CBSH)], 1);
    }
    __syncthreads();
    for (int i = threadIdx.x; i < NBC; i += 256) {
        int v = h[i] + h[NBC + i] + h[2 * NBC + i] + h[3 * NBC + i];
        if (v) atomicAdd(&dst[i], v);
    }
}

// merged scan: block 0 -> feat, block 1 -> edge
__global__ __launch_bounds__(256) void scan2_k(const int* __restrict__ cbf,
                                               int* __restrict__ cbasef, int* __restrict__ gbf,
                                               int* __restrict__ frp,
                                               const int* __restrict__ cbe,
                                               int* __restrict__ cbasee, int* __restrict__ gbe,
                                               int* __restrict__ erp) {
    const int* cnt; int* cbase; int* gbcur; int* rp;
    if (blockIdx.x == 0) { cnt = cbf; cbase = cbasef; gbcur = gbf; rp = frp; }
    else                 { cnt = cbe; cbase = cbasee; gbcur = gbe; rp = erp; }
    __shared__ int s[256];
    int t = threadIdx.x;
    int v = (t < NBC) ? cnt[t] : 0;
    s[t] = v;
    __syncthreads();
    for (int off = 1; off < 256; off <<= 1) {
        int a = (t >= off) ? s[t - off] : 0;
        __syncthreads();
        s[t] += a;
        __syncthreads();
    }
    if (t < NBC) { cbase[t] = s[t] - v; gbcur[t] = s[t] - v; }
    if (t == NBC - 1) { cbase[NBC] = s[t]; rp[N_NODES] = s[t]; }
}

// merged binA: 1024 threads, TILE 8192, vectorized input streams.
__global__ __launch_bounds__(1024) void binA2_k(
    const int* __restrict__ frows, const int* __restrict__ fcols, const float* __restrict__ fvals,
    int* __restrict__ gbf, int* __restrict__ fpk, unsigned short* __restrict__ frl,
    const int* __restrict__ erows, const int* __restrict__ ecols, const float* __restrict__ evals,
    int* __restrict__ gbe, int* __restrict__ epk, unsigned short* __restrict__ erl)
{
    __shared__ int            staged_pk[TILE];   // 32 KB
    __shared__ unsigned short staged_rl[TILE];   // 16 KB
    __shared__ unsigned char  sbkt[TILE];        //  8 KB
    __shared__ int cnt[NBC];
    __shared__ int rstart[NBC];
    __shared__ int gbase[NBC];
    __shared__ int sc[256];

    const int* rows; const int* cols; const float* vals;
    int* gbcur; int* bpk; unsigned short* brl;
    int n, qshift, bfval; float qmul;
    int bid = blockIdx.x;
    if (bid < NFB) {
        rows = frows; cols = fcols; vals = fvals; gbcur = gbf; bpk = fpk; brl = frl;
        n = NNZ_FEAT; qshift = 16; qmul = 0.f; bfval = 1;
    } else {
        bid -= NFB;
        rows = erows; cols = ecols; vals = evals; gbcur = gbe; bpk = epk; brl = erl;
        n = N_EDGES; qshift = 17; qmul = EQMUL; bfval = 0;
    }

    int tid = threadIdx.x;
    int base = bid * TILE;
    int m = n - base; if (m > TILE) m = TILE;

    for (int i = tid; i < NBC; i += 1024) cnt[i] = 0;
    __syncthreads();

    int rbuf[8]; int cbuf[8]; float vbuf[8]; int seq[8];
    int j0 = tid * 8;
    if (m == TILE) {
        const int4* r4 = reinterpret_cast<const int4*>(rows + base) + tid * 2;
        const int4* c4 = reinterpret_cast<const int4*>(cols + base) + tid * 2;
        const float4* v4 = reinterpret_cast<const float4*>(vals + base) + tid * 2;
        int4 ra = r4[0], rb = r4[1];
        int4 ca = c4[0], cb = c4[1];
        float4 va = v4[0], vb = v4[1];
        rbuf[0]=ra.x; rbuf[1]=ra.y; rbuf[2]=ra.z; rbuf[3]=ra.w;
        rbuf[4]=rb.x; rbuf[5]=rb.y; rbuf[6]=rb.z; rbuf[7]=rb.w;
        cbuf[0]=ca.x; cbuf[1]=ca.y; cbuf[2]=ca.z; cbuf[3]=ca.w;
        cbuf[4]=cb.x; cbuf[5]=cb.y; cbuf[6]=cb.z; cbuf[7]=cb.w;
        vbuf[0]=va.x; vbuf[1]=va.y; vbuf[2]=va.z; vbuf[3]=va.w;
        vbuf[4]=vb.x; vbuf[5]=vb.y; vbuf[6]=vb.z; vbuf[7]=vb.w;
    } else {
        #pragma unroll
        for (int k = 0; k < 8; ++k) {
            int j = j0 + k;
            if (j < m) { rbuf[k] = rows[base + j]; cbuf[k] = cols[base + j]; vbuf[k] = vals[base + j]; }
        }
    }
    #pragma unroll
    for (int k = 0; k < 8; ++k) {
        int j = j0 + k;
        if (j < m) seq[k] = atomicAdd(&cnt[rbuf[k] >> CBSH], 1);
    }
    __syncthreads();

    if (tid < 256) sc[tid] = (tid < NBC) ? cnt[tid] : 0;
    __syncthreads();
    for (int off = 1; off < 256; off <<= 1) {
        int a = 0;
        if (tid < 256 && tid >= off) a = sc[tid - off];
        __syncthreads();
        if (tid < 256) sc[tid] += a;
        __syncthreads();
    }
    if (tid < NBC) rstart[tid] = sc[tid] - cnt[tid];
    __syncthreads();

    #pragma unroll
    for (int k = 0; k < 8; ++k) {
        int j = j0 + k;
        if (j < m) {
            int r = rbuf[k];
            int b = r >> CBSH;
            int q = bfval ? (int)f2bf(vbuf[k]) : __float2int_rn(vbuf[k] * qmul);
            int slot = rstart[b] + seq[k];
            staged_pk[slot] = (q << qshift) | cbuf[k];
            staged_rl[slot] = (unsigned short)(r & (CROWS - 1));
            sbkt[slot] = (unsigned char)b;
        }
    }
    __syncthreads();

    if (tid < NBC && cnt[tid] > 0) gbase[tid] = atomicAdd(&gbcur[tid], cnt[tid]);
    __syncthreads();

    #pragma unroll
    for (int k = 0; k < 8; ++k) {
        int slot = k * 1024 + tid;
        if (slot < m) {
            int b = sbkt[slot];
            int dst = gbase[b] + (slot - rstart[b]);
            bpk[dst] = staged_pk[slot];
            brl[dst] = staged_rl[slot];
        }
    }
}

// merged binB: LDS-staged within-bucket permutation -> contiguous global writes.
__global__ __launch_bounds__(1024) void binB3_k(
    const int* __restrict__ fpk, const unsigned short* __restrict__ frl,
    const int* __restrict__ cbasef, int* __restrict__ frp, int* __restrict__ fcw,
    const int* __restrict__ epk, const unsigned short* __restrict__ erl,
    const int* __restrict__ cbasee, int* __restrict__ erp, int* __restrict__ ecw)
{
    const int* bin_pk; const unsigned short* bin_rl; const int* cbase; int* rp; int* cw;
    int b = blockIdx.x;
    if (b < NBC) { bin_pk = fpk; bin_rl = frl; cbase = cbasef; rp = frp; cw = fcw; }
    else { b -= NBC; bin_pk = epk; bin_rl = erl; cbase = cbasee; rp = erp; cw = ecw; }

    int r0 = b << CBSH;
    int nrows = N_NODES - r0; if (nrows > CROWS) nrows = CROWS;
    __shared__ int staged[BCAP];          // 112 KB
    __shared__ int hist[CROWS];
    __shared__ int sc[CROWS];
    int t = threadIdx.x;
    if (t < CROWS) hist[t] = 0;
    __syncthreads();
    int s = cbase[b], e = cbase[b + 1];
    int cnt = e - s;
    for (int i = s + t; i < e; i += 1024)
        atomicAdd(&hist[bin_rl[i]], 1);
    __syncthreads();
    if (t < CROWS) sc[t] = hist[t];
    __syncthreads();
    for (int off = 1; off < CROWS; off <<= 1) {
        int a = (t >= off && t < CROWS) ? sc[t - off] : 0;
        __syncthreads();
        if (t < CROWS) sc[t] += a;
        __syncthreads();
    }
    if (t < CROWS) {
        int excl = sc[t] - hist[t];
        if (t < nrows) rp[r0 + t] = excl + s;
        hist[t] = excl;
    }
    __syncthreads();

    if (cnt <= BCAP) {
        for (int i = s + t; i < e; i += 1024) {
            int pos = atomicAdd(&hist[bin_rl[i]], 1);
            staged[pos] = bin_pk[i];
        }
        __syncthreads();
        for (int j = t; j < cnt; j += 1024)
            cw[s + j] = staged[j];
    } else {
        for (int i = s + t; i < e; i += 1024) {
            int pos = atomicAdd(&hist[bin_rl[i]], 1);
            cw[s + pos] = bin_pk[i];
        }
    }
}

// ======================= compute kernels =======================

__global__ __launch_bounds__(256) void w1_to_fp8(const float* __restrict__ W1,
                                                 unsigned char* __restrict__ W1q) {
    int t = blockIdx.x * 256 + threadIdx.x;
    if (t < N_FEATURES * HIDDEN / 4) {
        float4 v = reinterpret_cast<const float4*>(W1)[t];
        uchar4 o;
        o.x = f2fp8(v.x); o.y = f2fp8(v.y); o.z = f2fp8(v.z); o.w = f2fp8(v.w);
        reinterpret_cast<uchar4*>(W1q)[t] = o;
    }
}

// Fused SpMM+MLP: 8 lanes/row, 8 hidden dims/lane, W1 fp8 L2-gather (64B row = 1 txn).
__global__ __launch_bounds__(256) void spmm_fused(const int* __restrict__ rp,
                                                  const int* __restrict__ cwp,
                                                  const unsigned char* __restrict__ W1q,
                                                  const float* __restrict__ b1,
                                                  const float* __restrict__ W2,
                                                  const float* __restrict__ b2,
                                                  unsigned short* __restrict__ az,
                                                  unsigned short* __restrict__ pb0) {
    __shared__ float sW2T[N_LABELS * (HIDDEN + 1)];   // [l][h], stride 65
    __shared__ float sb1[HIDDEN];
    __shared__ float sb2[N_LABELS];
    for (int i = threadIdx.x; i < HIDDEN * N_LABELS; i += 256) {
        int h = i >> 4, l = i & 15;
        sW2T[l * (HIDDEN + 1) + h] = W2[i];
    }
    if (threadIdx.x < HIDDEN) sb1[threadIdx.x] = b1[threadIdx.x];
    if (threadIdx.x < N_LABELS) sb2[threadIdx.x] = b2[threadIdx.x];
    __syncthreads();

    int t = blockIdx.x * 256 + threadIdx.x;
    int row = t >> 3, sl = t & 7;
    if (row >= N_NODES) return;
    int s = rp[row], e = rp[row + 1];
    int hbase = sl * 8;

    float acc[8];
    #pragma unroll
    for (int j = 0; j < 8; ++j) acc[j] = 0.f;

    int i = s;
    for (; i + 3 < e; i += 4) {
        uint2 wv[4]; float vv[4];
        #pragma unroll
        for (int k = 0; k < 4; ++k) {
            int pk = cwp[i + k];
            vv[k] = bf_hi((unsigned)pk);
            wv[k] = *reinterpret_cast<const uint2*>(W1q + (size_t)(pk & 0x7FF) * HIDDEN + hbase);
        }
        #pragma unroll
        for (int k = 0; k < 4; ++k) {
            acc[0] = fmaf(vv[k], FP8DEC(wv[k].x, 0), acc[0]);
            acc[1] = fmaf(vv[k], FP8DEC(wv[k].x, 1), acc[1]);
            acc[2] = fmaf(vv[k], FP8DEC(wv[k].x, 2), acc[2]);
            acc[3] = fmaf(vv[k], FP8DEC(wv[k].x, 3), acc[3]);
            acc[4] = fmaf(vv[k], FP8DEC(wv[k].y, 0), acc[4]);
            acc[5] = fmaf(vv[k], FP8DEC(wv[k].y, 1), acc[5]);
            acc[6] = fmaf(vv[k], FP8DEC(wv[k].y, 2), acc[6]);
            acc[7] = fmaf(vv[k], FP8DEC(wv[k].y, 3), acc[7]);
        }
    }
    for (; i < e; ++i) {
        int pk = cwp[i];
        float v = bf_hi((unsigned)pk);
        uint2 w = *reinterpret_cast<const uint2*>(W1q + (size_t)(pk & 0x7FF) * HIDDEN + hbase);
        acc[0] = fmaf(v, FP8DEC(w.x, 0), acc[0]);
        acc[1] = fmaf(v, FP8DEC(w.x, 1), acc[1]);
        acc[2] = fmaf(v, FP8DEC(w.x, 2), acc[2]);
        acc[3] = fmaf(v, FP8DEC(w.x, 3), acc[3]);
        acc[4] = fmaf(v, FP8DEC(w.y, 0), acc[4]);
        acc[5] = fmaf(v, FP8DEC(w.y, 1), acc[5]);
        acc[6] = fmaf(v, FP8DEC(w.y, 2), acc[6]);
        acc[7] = fmaf(v, FP8DEC(w.y, 3), acc[7]);
    }

    float part[16];
    #pragma unroll
    for (int l = 0; l < 16; ++l) part[l] = 0.f;
    #pragma unroll
    for (int j = 0; j < 8; ++j) {
        float a = fmaf(acc[j], 0.0625f, sb1[hbase + j]);   // un-scale fp8 x16
        a = a > 0.f ? a : 0.f;
        #pragma unroll
        for (int l = 0; l < 16; ++l)
            part[l] = fmaf(a, sW2T[l * (HIDDEN + 1) + hbase + j], part[l]);
    }
    #pragma unroll
    for (int l = 0; l < 8; ++l) {
        float lo = __shfl_xor(part[l], 1);
        float hi = __shfl_xor(part[l + 8], 1);
        part[l] = (sl & 1) ? (part[l + 8] + hi) : (part[l] + lo);
    }
    #pragma unroll
    for (int l = 0; l < 4; ++l) {
        float lo = __shfl_xor(part[l], 2);
        float hi = __shfl_xor(part[l + 4], 2);
        part[l] = (sl & 2) ? (part[l + 4] + hi) : (part[l] + lo);
    }
    #pragma unroll
    for (int l = 0; l < 2; ++l) {
        float lo = __shfl_xor(part[l], 4);
        float hi = __shfl_xor(part[l + 2], 4);
        part[l] = (sl & 4) ? (part[l + 2] + hi) : (part[l] + lo);
    }
    int lbase = 8 * (sl & 1) + 4 * ((sl >> 1) & 1) + 2 * ((sl >> 2) & 1);
    float z0 = part[0] + sb2[lbase];
    float z1 = part[1] + sb2[lbase + 1];
    unsigned oz = (unsigned)f2bf(z0) | ((unsigned)f2bf(z1) << 16);
    unsigned oa = (unsigned)f2bf(ALPHA * z0) | ((unsigned)f2bf(ALPHA * z1) << 16);
    *reinterpret_cast<unsigned*>(pb0 + (size_t)row * N_LABELS + lbase) = oz;
    *reinterpret_cast<unsigned*>(az  + (size_t)row * N_LABELS + lbase) = oa;
}

// 8 lanes/row, 4B gathers (plain loads -> L2-cached p); cw via lane-parallel + shfl.
__global__ __launch_bounds__(256) void prop_bf16(const int* __restrict__ rp,
                                                 const int* __restrict__ cwp,
                                                 const unsigned short* __restrict__ az,
                                                 const unsigned short* __restrict__ pin,
                                                 unsigned short* __restrict__ pout) {
    int t = blockIdx.x * 256 + threadIdx.x;
    int row = t >> 3, sub = t & 7;
    if (row >= N_NODES) return;
    int s = rp[row], e = rp[row + 1];
    unsigned azw = *reinterpret_cast<const unsigned*>(az + (size_t)row * N_LABELS + sub * 2);
    float a0 = bf_lo(azw), a1 = bf_hi(azw);
    int i = s;
    for (; i + 7 < e; i += 8) {
        int cwv = cwp[i + sub];             // lane-parallel, 32B coalesced per group
        unsigned q[8]; float w[8];
        #pragma unroll
        for (int k = 0; k < 8; ++k) {
            int pk = __shfl(cwv, k, 8);
            w[k] = (float)((unsigned)pk >> 17) * EWDEC;
            q[k] = *reinterpret_cast<const unsigned*>(pin + (size_t)(pk & 0x1FFFF) * N_LABELS + sub * 2);
        }
        #pragma unroll
        for (int k = 0; k < 8; ++k) {
            a0 = fmaf(w[k], bf_lo(q[k]), a0);
            a1 = fmaf(w[k], bf_hi(q[k]), a1);
        }
    }
    for (; i < e; ++i) {
        int pk = cwp[i];
        float w = (float)((unsigned)pk >> 17) * EWDEC;
        unsigned q = *reinterpret_cast<const unsigned*>(pin + (size_t)(pk & 0x1FFFF) * N_LABELS + sub * 2);
        a0 = fmaf(w, bf_lo(q), a0);
        a1 = fmaf(w, bf_hi(q), a1);
    }
    *reinterpret_cast<unsigned*>(pout + (size_t)row * N_LABELS + sub * 2) =
        (unsigned)f2bf(a0) | ((unsigned)f2bf(a1) << 16);
}

// last iteration fused with log_softmax (8-lane shuffle reduce); writes f32 out
__global__ __launch_bounds__(256) void prop_final(const int* __restrict__ rp,
                                                  const int* __restrict__ cwp,
                                                  const unsigned short* __restrict__ az,
                                                  const unsigned short* __restrict__ pin,
                                                  float* __restrict__ out) {
    int t = blockIdx.x * 256 + threadIdx.x;
    int row = t >> 3, sub = t & 7;
    if (row >= N_NODES) return;
    int s = rp[row], e = rp[row + 1];
    unsigned azw = *reinterpret_cast<const unsigned*>(az + (size_t)row * N_LABELS + sub * 2);
    float a0 = bf_lo(azw), a1 = bf_hi(azw);
    int i = s;
    for (; i + 7 < e; i += 8) {
        int cwv = cwp[i + sub];
        unsigned q[8]; float w[8];
        #pragma unroll
        for (int k = 0; k < 8; ++k) {
            int pk = __shfl(cwv, k, 8);
            w[k] = (float)((unsigned)pk >> 17) * EWDEC;
            q[k] = *reinterpret_cast<const unsigned*>(pin + (size_t)(pk & 0x1FFFF) * N_LABELS + sub * 2);
        }
        #pragma unroll
        for (int k = 0; k < 8; ++k) {
            a0 = fmaf(w[k], bf_lo(q[k]), a0);
            a1 = fmaf(w[k], bf_hi(q[k]), a1);
        }
    }
    for (; i < e; ++i) {
        int pk = cwp[i];
        float w = (float)((unsigned)pk >> 17) * EWDEC;
        unsigned q = *reinterpret_cast<const unsigned*>(pin + (size_t)(pk & 0x1FFFF) * N_LABELS + sub * 2);
        a0 = fmaf(w, bf_lo(q), a0);
        a1 = fmaf(w, bf_hi(q), a1);
    }
    float m = fmaxf(a0, a1);
    m = fmaxf(m, __shfl_xor(m, 1));
    m = fmaxf(m, __shfl_xor(m, 2));
    m = fmaxf(m, __shfl_xor(m, 4));
    float ssum = __expf(a0 - m) + __expf(a1 - m);
    ssum += __shfl_xor(ssum, 1);
    ssum += __shfl_xor(ssum, 2);
    ssum += __shfl_xor(ssum, 4);
    float lse = m + __logf(ssum);
    *reinterpret_cast<float2*>(out + (size_t)row * N_LABELS + sub * 2) =
        make_float2(a0 - lse, a1 - lse);
}

// ======================= fallback (atomic path) =======================

__global__ __launch_bounds__(256) void zero_f4(float4* __restrict__ p, int n4) {
    int t = blockIdx.x * 256 + threadIdx.x;
    if (t < n4) p[t] = make_float4(0.f, 0.f, 0.f, 0.f);
}

__global__ __launch_bounds__(256) void spmm_feat_atomic(
    const int* __restrict__ rows, const int* __restrict__ cols,
    const float* __restrict__ vals, const float* __restrict__ W1,
    float* __restrict__ latent)
{
    long long t = (long long)blockIdx.x * 256 + threadIdx.x;
    if (t >= (long long)NNZ_FEAT * 16) return;
    int e  = (int)(t >> 4);
    int dg = (int)(t & 15);
    int r = rows[e]; int c = cols[e]; float v = vals[e];
    float4 w = *reinterpret_cast<const float4*>(W1 + (size_t)c * HIDDEN + dg * 4);
    float* dst = latent + (size_t)r * HIDDEN + dg * 4;
    atomicAdd(dst + 0, v * w.x); atomicAdd(dst + 1, v * w.y);
    atomicAdd(dst + 2, v * w.z); atomicAdd(dst + 3, v * w.w);
}

__global__ __launch_bounds__(256) void compute_z(const float* __restrict__ latent,
                                                 const float* __restrict__ b1,
                                                 const float* __restrict__ W2,
                                                 const float* __restrict__ b2,
                                                 float* __restrict__ z) {
    __shared__ float sW2[HIDDEN * N_LABELS];
    __shared__ float sb1[HIDDEN];
    for (int i = threadIdx.x; i < HIDDEN * N_LABELS; i += 256) sW2[i] = W2[i];
    if (threadIdx.x < HIDDEN) sb1[threadIdx.x] = b1[threadIdx.x];
    __syncthreads();
    int t = blockIdx.x * 256 + threadIdx.x;
    int node = t >> 4;
    int l = t & 15;
    if (node >= N_NODES) return;
    float acc = b2[l];
    const float* lat = latent + (size_t)node * HIDDEN;
    #pragma unroll 8
    for (int h = 0; h < HIDDEN; ++h) {
        float a = lat[h] + sb1[h];
        a = a > 0.f ? a : 0.f;
        acc = fmaf(a, sW2[h * N_LABELS + l], acc);
    }
    z[(size_t)node * N_LABELS + l] = acc;
}

__global__ __launch_bounds__(256) void init_acc(const float* __restrict__ z,
                                                float* __restrict__ acc) {
    int t = blockIdx.x * 256 + threadIdx.x;
    if (t < N_NODES * N_LABELS / 4) {
        float4 zv = reinterpret_cast<const float4*>(z)[t];
        reinterpret_cast<float4*>(acc)[t] =
            make_float4(ALPHA * zv.x, ALPHA * zv.y, ALPHA * zv.z, ALPHA * zv.w);
    }
}

__global__ __launch_bounds__(256) void edge_scatter(
    const int* __restrict__ rows, const int* __restrict__ cols,
    const float* __restrict__ w, const float* __restrict__ p,
    float* __restrict__ acc)
{
    long long t = (long long)blockIdx.x * 256 + threadIdx.x;
    if (t >= (long long)N_EDGES * 4) return;
    int e = (int)(t >> 2);
    int part = (int)(t & 3);
    int r = rows[e]; int c = cols[e];
    float wt = w[e] * (1.0f - ALPHA);
    float4 pv = *reinterpret_cast<const float4*>(p + (size_t)c * N_LABELS + part * 4);
    float* dst = acc + (size_t)r * N_LABELS + part * 4;
    atomicAdd(dst + 0, wt * pv.x); atomicAdd(dst + 1, wt * pv.y);
    atomicAdd(dst + 2, wt * pv.z); atomicAdd(dst + 3, wt * pv.w);
}

__global__ __launch_bounds__(256) void logsoftmax_k(const float* __restrict__ p,
                                                    float* __restrict__ out) {
    int node = blockIdx.x * 256 + threadIdx.x;
    if (node >= N_NODES) return;
    const float4* src = reinterpret_cast<const float4*>(p + (size_t)node * N_LABELS);
    float4 a = src[0], b = src[1], c = src[2], d = src[3];
    float x[16] = {a.x,a.y,a.z,a.w, b.x,b.y,b.z,b.w, c.x,c.y,c.z,c.w, d.x,d.y,d.z,d.w};
    float m = x[0];
    #pragma unroll
    for (int i = 1; i < 16; ++i) m = fmaxf(m, x[i]);
    float s = 0.f;
    #pragma unroll
    for (int i = 0; i < 16; ++i) s += expf(x[i] - m);
    float lse = m + logf(s);
    float4* o = reinterpret_cast<float4*>(out + (size_t)node * N_LABELS);
    o[0] = make_float4(x[0]-lse,  x[1]-lse,  x[2]-lse,  x[3]-lse);
    o[1] = make_float4(x[4]-lse,  x[5]-lse,  x[6]-lse,  x[7]-lse);
    o[2] = make_float4(x[8]-lse,  x[9]-lse,  x[10]-lse, x[11]-lse);
    o[3] = make_float4(x[12]-lse, x[13]-lse, x[14]-lse, x[15]-lse);
}

// ======================= launch =======================

extern "C" void kernel_launch(void* const* d_in, const int* in_sizes, int n_in,
                              void* d_out, int out_size, void* d_ws, size_t ws_size,
                              hipStream_t stream)
{
    const int*   feat_rows = (const int*)d_in[0];
    const int*   feat_cols = (const int*)d_in[1];
    const float* feat_vals = (const float*)d_in[2];
    const int*   edge_rows = (const int*)d_in[3];
    const int*   edge_cols = (const int*)d_in[4];
    const float* edge_w    = (const float*)d_in[5];
    const float* W1 = (const float*)d_in[6];
    const float* b1 = (const float*)d_in[7];
    const float* W2 = (const float*)d_in[8];
    const float* b2 = (const float*)d_in[9];
    float* out = (float*)d_out;

    // ---- workspace layout (4-byte words) ----
    size_t need = 0;
    size_t o_feat_cw = need; need += (size_t)NNZ_FEAT;            // packed int32, 20 MB
    size_t o_edge_cw = need; need += (size_t)N_EDGES;             // packed int32, 12.8 MB
    size_t o_latent  = need; need += (size_t)N_NODES * HIDDEN;    // 25.6 MB (fallback + feat-bin alias)
    size_t o_z       = need; need += (size_t)N_NODES * N_LABELS;  // az (bf16) + feat_rl alias
    size_t o_p0      = need; need += (size_t)N_NODES * N_LABELS;
    size_t o_p1      = need; need += (size_t)N_NODES * N_LABELS;
    size_t o_frp     = need; need += N_NODES + 1;
    size_t o_erp     = need; need += N_NODES + 1;
    size_t o_w1q     = need; need += (size_t)N_FEATURES * HIDDEN / 4;  // fp8 W1, 128 KB
    size_t o_ebin_pk = need; need += (size_t)N_EDGES;             // dedicated edge bin, 12.8 MB
    size_t o_ebin_rl = need; need += (size_t)N_EDGES / 2;         // 6.4 MB
    size_t o_cbf     = need; need += NBC;
    size_t o_cbe     = need; need += NBC;
    size_t o_cbasef  = need; need += NBC + 1;
    size_t o_cbasee  = need; need += NBC + 1;
    size_t o_gbf     = need; need += NBC;
    size_t o_gbe     = need; need += NBC;
    size_t need_bytes = need * 4 + 64;

    float* base = (float*)d_ws;
    float* latent = base + o_latent;
    float* z  = base + o_z;
    float* p0 = base + o_p0;
    float* p1 = base + o_p1;

    if (ws_size >= need_bytes) {
        int* feat_cw = (int*)(base + o_feat_cw);
        int* edge_cw = (int*)(base + o_edge_cw);
        int* feat_rp = (int*)(base + o_frp);
        int* edge_rp = (int*)(base + o_erp);
        unsigned char* W1q = (unsigned char*)(base + o_w1q);
        int* cbf    = (int*)(base + o_cbf);
        int* cbe    = (int*)(base + o_cbe);
        int* cbasef = (int*)(base + o_cbasef);
        int* cbasee = (int*)(base + o_cbasee);
        int* gbf    = (int*)(base + o_gbf);
        int* gbe    = (int*)(base + o_gbe);
        int*            fbin_pk = (int*)(base + o_latent);            // 5M ints <= 6.4M
        unsigned short* fbin_rl = (unsigned short*)(base + o_z);      // 5M shorts <= 6.4M (z+p0)
        int*            ebin_pk = (int*)(base + o_ebin_pk);
        unsigned short* ebin_rl = (unsigned short*)(base + o_ebin_rl);
        unsigned short* az  = (unsigned short*)z;                     // bf16 anchor, 3.2 MB
        unsigned short* pb0 = (unsigned short*)p0;
        unsigned short* pb1 = (unsigned short*)p1;

        // ---- merged CSR builds ----
        w1_to_fp8<<<(N_FEATURES * HIDDEN / 4 + 255) / 256, 256, 0, stream>>>(W1, W1q);
        zero_int<<<2, 256, 0, stream>>>(cbf, 2 * NBC);   // cbf,cbe adjacent
        hist2_k<<<2048, 256, 0, stream>>>(feat_rows, NNZ_FEAT, cbf, edge_rows, N_EDGES, cbe);
        scan2_k<<<2, 256, 0, stream>>>(cbf, cbasef, gbf, feat_rp, cbe, cbasee, gbe, edge_rp);
        binA2_k<<<NFB + NEB, 1024, 0, stream>>>(
            feat_rows, feat_cols, feat_vals, gbf, fbin_pk, fbin_rl,
            edge_rows, edge_cols, edge_w, gbe, ebin_pk, ebin_rl);
        binB3_k<<<2 * NBC, 1024, 0, stream>>>(
            fbin_pk, fbin_rl, cbasef, feat_rp, feat_cw,
            ebin_pk, ebin_rl, cbasee, edge_rp, edge_cw);

        // ---- layer 1 + z (fused; writes az bf16 + p0 bf16) ----
        spmm_fused<<<(N_NODES * 8 + 255) / 256, 256, 0, stream>>>(
            feat_rp, feat_cw, W1q, b1, W2, b2, az, pb0);

        // ---- propagation (bf16 state, 8 lanes/row) ----
        const unsigned short* pin = pb0;
        int pgrid = (N_NODES * 8 + 255) / 256;
        for (int it = 0; it < ITERS - 1; ++it) {
            unsigned short* pout = (it & 1) ? pb0 : pb1;
            prop_bf16<<<pgrid, 256, 0, stream>>>(edge_rp, edge_cw, az, pin, pout);
            pin = pout;
        }
        prop_final<<<pgrid, 256, 0, stream>>>(edge_rp, edge_cw, az, pin, out);
    } else {
        // ---- fallback: atomic path ----
        int n4 = N_NODES * HIDDEN / 4;
        zero_f4<<<(n4 + 255) / 256, 256, 0, stream>>>((float4*)latent, n4);
        long long total = (long long)NNZ_FEAT * 16;
        spmm_feat_atomic<<<(int)((total + 255) / 256), 256, 0, stream>>>(
            feat_rows, feat_cols, feat_vals, W1, latent);
        compute_z<<<N_NODES * 16 / 256, 256, 0, stream>>>(latent, b1, W2, b2, z);
        const float* pin = z;
        float* bufs[2] = {p0, p1};
        for (int it = 0; it < ITERS; ++it) {
            float* pout = bufs[it & 1];
            init_acc<<<(N_NODES * N_LABELS / 4 + 255) / 256, 256, 0, stream>>>(z, pout);
            long long tot = (long long)N_EDGES * 4;
            edge_scatter<<<(int)((tot + 255) / 256), 256, 0, stream>>>(
                edge_rows, edge_cols, edge_w, pin, pout);
            pin = pout;
        }
        logsoftmax_k<<<(N_NODES + 255) / 256, 256, 0, stream>>>(pin, out);
    }
}